// Round 13
// baseline (73.576 us; speedup 1.0000x reference)
//
#include <hip/hip_runtime.h>
#include <math.h>

#define B_ 8
#define C_ 64
#define K_ 32
#define HW_ 16384
#define CHUNK_ 128
#define NCHUNKOUT_ 64        // 64 partial slabs per batch
#define LDN 132              // padded [c][n] row stride (floats)
#define TILE_ 256            // fusion px tile
#define NEG_SLOPE_ 0.1f

// ws layout:
//   [0, 8MB)          float partial[B_][NCHUNKOUT_][C_][C_]
//   [8MB, 8MB+64KB)   int   idxb[B_][C_][K_]

// corr (R6-measured config, ~22us): [c][n] LDN=132 block staging, 4x4
// register tile, 2 halves of 128 n per block.
__global__ __launch_bounds__(256, 2) void corr_partial_kernel(
    const float* __restrict__ LR, const float* __restrict__ HR,
    float* __restrict__ partial)
{
    __shared__ float lrS[C_][LDN];
    __shared__ float hrS[C_][LDN];
    const int blk = blockIdx.x;
    const int b = blk >> 6;
    const int j = blk & 63;
    const int t = threadIdx.x;

    const int cq = t >> 4;           // 0..15
    const int dq = t & 15;           // 0..15
    float acc[4][4] = {};

    for (int half = 0; half < 2; ++half) {
        const int n0 = (j * 2 + half) * CHUNK_;
        if (half) __syncthreads();
        #pragma unroll
        for (int p = 0; p < 8; ++p) {
            const int f = p * 256 + t;
            const int c = f >> 5;
            const int q = f & 31;
            *reinterpret_cast<float4*>(&lrS[c][q * 4]) =
                *reinterpret_cast<const float4*>(&LR[(size_t)(b * C_ + c) * HW_ + n0 + q * 4]);
            *reinterpret_cast<float4*>(&hrS[c][q * 4]) =
                *reinterpret_cast<const float4*>(&HR[(size_t)(b * C_ + c) * HW_ + n0 + q * 4]);
        }
        __syncthreads();

        for (int nq = 0; nq < 32; ++nq) {
            float4 lv[4], hv[4];
            #pragma unroll
            for (int i = 0; i < 4; ++i)
                lv[i] = *reinterpret_cast<const float4*>(&lrS[cq + 16 * i][nq * 4]);
            #pragma unroll
            for (int jj = 0; jj < 4; ++jj)
                hv[jj] = *reinterpret_cast<const float4*>(&hrS[dq + 16 * jj][nq * 4]);
            #pragma unroll
            for (int i = 0; i < 4; ++i) {
                const float l[4] = {lv[i].x, lv[i].y, lv[i].z, lv[i].w};
                #pragma unroll
                for (int jj = 0; jj < 4; ++jj) {
                    const float h[4] = {hv[jj].x, hv[jj].y, hv[jj].z, hv[jj].w};
                    acc[i][jj] = fmaf(l[0], h[0], acc[i][jj]);
                    acc[i][jj] = fmaf(l[1], h[1], acc[i][jj]);
                    acc[i][jj] = fmaf(l[2], h[2], acc[i][jj]);
                    acc[i][jj] = fmaf(l[3], h[3], acc[i][jj]);
                }
            }
        }
    }

    float* P = partial + (size_t)(b * NCHUNKOUT_ + j) * (C_ * C_);
    #pragma unroll
    for (int i = 0; i < 4; ++i)
        #pragma unroll
        for (int jj = 0; jj < 4; ++jj)
            P[(cq + 16 * i) * C_ + (dq + 16 * jj)] = acc[i][jj];
}

// Reduce partials (f64, deterministic), rank channels per (b,c) like lax.top_k
// (stable descending), emit top-K channel indices. (R6-measured, ~4us)
__global__ __launch_bounds__(64) void rank_kernel(
    const float* __restrict__ partial, int* __restrict__ idxb)
{
    __shared__ double vals[C_];
    const int blk = blockIdx.x;     // b*64 + c
    const int b = blk >> 6;
    const int c = blk & 63;
    const int d = threadIdx.x;

    double acc = 0.0;
    for (int k = 0; k < NCHUNKOUT_; ++k)
        acc += (double)partial[(size_t)(b * NCHUNKOUT_ + k) * (C_ * C_) + c * C_ + d];
    vals[d] = acc;
    __syncthreads();

    int r = 0;
    for (int jj = 0; jj < C_; ++jj) {
        const double vj = vals[jj];
        r += (int)((vj > acc) || (vj == acc && jj < d));   // stable descending rank
    }
    if (r < K_) idxb[blk * K_ + r] = d;
}

// fusion v4: 256 blocks x 512 t; each block processes 2 consecutive px-tiles
// with a register-prefetch pipeline: tile t+1's 8 float4 global loads are
// issued right after tile t's RAW barrier and fly under the 2048-b128 gather.
__global__ __launch_bounds__(512, 1) void fusion_gather_kernel(
    const float* __restrict__ HR, const float* __restrict__ LR,
    const int* __restrict__ idxb,
    const float* __restrict__ w1, const float* __restrict__ b1,
    const float* __restrict__ w2, const float* __restrict__ b2,
    float* __restrict__ out)
{
    __shared__ float hrS[C_][TILE_];   // 64 KB

    const int t = threadIdx.x;
    const int bid = blockIdx.x;        // 256 blocks; tiles 2*bid, 2*bid+1
    const int g0 = bid * 2;
    const int b = g0 >> 6;             // both tiles in same batch (64 tiles/batch)
    const float* HRb = HR + (size_t)b * C_ * HW_;

    // per-thread staging coords (8 float4 per tile)
    int sc[8], sq[8];
    #pragma unroll
    for (int i = 0; i < 8; ++i) {
        const int f = i * 512 + t;
        sc[i] = f >> 6;                // channel 0..63
        sq[i] = (f & 63) * 4;          // col 0..252
    }

    float4 pre[8];
    {   // prologue: load tile 0
        const int px0 = (g0 & 63) * TILE_;
        #pragma unroll
        for (int i = 0; i < 8; ++i)
            pre[i] = *reinterpret_cast<const float4*>(&HRb[(size_t)sc[i] * HW_ + px0 + sq[i]]);
    }

    const int wv = t >> 6;             // wave id -> c-octant
    const int lane = t & 63;
    const int p4 = lane * 4;

    const int* idxc = idxb + b * C_ * K_;
    const float w10 = w1[0];
    const float b1v = b1[0], w2v = w2[0], b2v = b2[0];

    #pragma unroll 1
    for (int it = 0; it < 2; ++it) {
        const int px0 = ((g0 + it) & 63) * TILE_;
        if (it) __syncthreads();       // WAR: prev tile's gathers done
        #pragma unroll
        for (int i = 0; i < 8; ++i)
            *reinterpret_cast<float4*>(&hrS[sc[i]][sq[i]]) = pre[i];
        __syncthreads();               // RAW: slab visible

        if (it == 0) {                 // issue tile-1 loads; overlap the gather
            const int px1 = ((g0 + 1) & 63) * TILE_;
            #pragma unroll
            for (int i = 0; i < 8; ++i)
                pre[i] = *reinterpret_cast<const float4*>(&HRb[(size_t)sc[i] * HW_ + px1 + sq[i]]);
        }

        #pragma unroll 1
        for (int ci = 0; ci < 8; ++ci) {
            const int c = wv * 8 + ci;
            const float4 l4 = *reinterpret_cast<const float4*>(
                &LR[(size_t)(b * C_ + c) * HW_ + px0 + p4]);     // issue early
            float acc[4] = {0.f, 0.f, 0.f, 0.f};
            float mx[4]  = {-1e30f, -1e30f, -1e30f, -1e30f};
            #pragma unroll
            for (int k = 0; k < K_; ++k) {
                const int d = idxc[c * K_ + k];      // uniform -> s_load
                const float4 h = *reinterpret_cast<const float4*>(&hrS[d][p4]);
                const float wk = w1[k + 1];          // uniform -> SGPR
                acc[0] = fmaf(h.x, wk, acc[0]);
                acc[1] = fmaf(h.y, wk, acc[1]);
                acc[2] = fmaf(h.z, wk, acc[2]);
                acc[3] = fmaf(h.w, wk, acc[3]);
                mx[0] = fmaxf(mx[0], h.x);
                mx[1] = fmaxf(mx[1], h.y);
                mx[2] = fmaxf(mx[2], h.z);
                mx[3] = fmaxf(mx[3], h.w);
            }
            const float l[4] = {l4.x, l4.y, l4.z, l4.w};
            float o[4];
            #pragma unroll
            for (int p = 0; p < 4; ++p) {
                float f = fmaf(w10, l[p], acc[p]) + b1v;
                f = f >= 0.f ? f : NEG_SLOPE_ * f;
                f = fmaf(w2v, f, b2v);
                const float s = 1.f / (1.f + __expf(-mx[p]));
                o[p] = f * (1.f + s);
            }
            *reinterpret_cast<float4*>(&out[(size_t)(b * C_ + c) * HW_ + px0 + p4]) =
                make_float4(o[0], o[1], o[2], o[3]);
        }
    }
}

extern "C" void kernel_launch(void* const* d_in, const int* in_sizes, int n_in,
                              void* d_out, int out_size, void* d_ws, size_t ws_size,
                              hipStream_t stream)
{
    const float* HR = (const float*)d_in[0];
    const float* LR = (const float*)d_in[1];
    const float* w1 = (const float*)d_in[2];
    const float* b1 = (const float*)d_in[3];
    const float* w2 = (const float*)d_in[4];
    const float* b2 = (const float*)d_in[5];
    float* out = (float*)d_out;

    float* partial = (float*)d_ws;
    int* idxb = (int*)((char*)d_ws + (size_t)B_ * NCHUNKOUT_ * C_ * C_ * sizeof(float));

    corr_partial_kernel<<<B_ * 64, 256, 0, stream>>>(LR, HR, partial);
    rank_kernel<<<B_ * C_, 64, 0, stream>>>(partial, idxb);
    fusion_gather_kernel<<<B_ * (HW_ / TILE_) / 2, 512, 0, stream>>>(HR, LR, idxb, w1, b1, w2, b2, out);
}

// Round 14
// 61.581 us; speedup vs baseline: 1.1948x; 1.1948x over previous
//
#include <hip/hip_runtime.h>
#include <math.h>

#define B_ 8
#define C_ 64
#define K_ 32
#define HW_ 16384
#define CHUNK_ 128
#define NCHUNKOUT_ 64        // 64 partial slabs per batch
#define LDN 132              // padded [c][n] row stride (floats)
#define TILE_ 256            // fusion px tile
#define KSPLIT_ 24           // k < KSPLIT_ gathered from LDS, rest from global (L2)
#define NEG_SLOPE_ 0.1f

// ws layout:
//   [0, 8MB)          float partial[B_][NCHUNKOUT_][C_][C_]
//   [8MB, 8MB+64KB)   int   idxb[B_][C_][K_]

// corr (R6-measured, ~22us): [c][n] LDN=132 block staging, 4x4 register
// tile, 2 halves of 128 n per block. Do not touch (R7-R11 variants all
// regressed or were neutral).
__global__ __launch_bounds__(256, 2) void corr_partial_kernel(
    const float* __restrict__ LR, const float* __restrict__ HR,
    float* __restrict__ partial)
{
    __shared__ float lrS[C_][LDN];
    __shared__ float hrS[C_][LDN];
    const int blk = blockIdx.x;
    const int b = blk >> 6;
    const int j = blk & 63;
    const int t = threadIdx.x;

    const int cq = t >> 4;           // 0..15
    const int dq = t & 15;           // 0..15
    float acc[4][4] = {};

    for (int half = 0; half < 2; ++half) {
        const int n0 = (j * 2 + half) * CHUNK_;
        if (half) __syncthreads();
        #pragma unroll
        for (int p = 0; p < 8; ++p) {
            const int f = p * 256 + t;
            const int c = f >> 5;
            const int q = f & 31;
            *reinterpret_cast<float4*>(&lrS[c][q * 4]) =
                *reinterpret_cast<const float4*>(&LR[(size_t)(b * C_ + c) * HW_ + n0 + q * 4]);
            *reinterpret_cast<float4*>(&hrS[c][q * 4]) =
                *reinterpret_cast<const float4*>(&HR[(size_t)(b * C_ + c) * HW_ + n0 + q * 4]);
        }
        __syncthreads();

        for (int nq = 0; nq < 32; ++nq) {
            float4 lv[4], hv[4];
            #pragma unroll
            for (int i = 0; i < 4; ++i)
                lv[i] = *reinterpret_cast<const float4*>(&lrS[cq + 16 * i][nq * 4]);
            #pragma unroll
            for (int jj = 0; jj < 4; ++jj)
                hv[jj] = *reinterpret_cast<const float4*>(&hrS[dq + 16 * jj][nq * 4]);
            #pragma unroll
            for (int i = 0; i < 4; ++i) {
                const float l[4] = {lv[i].x, lv[i].y, lv[i].z, lv[i].w};
                #pragma unroll
                for (int jj = 0; jj < 4; ++jj) {
                    const float h[4] = {hv[jj].x, hv[jj].y, hv[jj].z, hv[jj].w};
                    acc[i][jj] = fmaf(l[0], h[0], acc[i][jj]);
                    acc[i][jj] = fmaf(l[1], h[1], acc[i][jj]);
                    acc[i][jj] = fmaf(l[2], h[2], acc[i][jj]);
                    acc[i][jj] = fmaf(l[3], h[3], acc[i][jj]);
                }
            }
        }
    }

    float* P = partial + (size_t)(b * NCHUNKOUT_ + j) * (C_ * C_);
    #pragma unroll
    for (int i = 0; i < 4; ++i)
        #pragma unroll
        for (int jj = 0; jj < 4; ++jj)
            P[(cq + 16 * i) * C_ + (dq + 16 * jj)] = acc[i][jj];
}

// Reduce partials (f64, deterministic), rank channels per (b,c) like lax.top_k
// (stable descending), emit top-K channel indices. (R6-measured, ~4us)
__global__ __launch_bounds__(64) void rank_kernel(
    const float* __restrict__ partial, int* __restrict__ idxb)
{
    __shared__ double vals[C_];
    const int blk = blockIdx.x;     // b*64 + c
    const int b = blk >> 6;
    const int c = blk & 63;
    const int d = threadIdx.x;

    double acc = 0.0;
    for (int k = 0; k < NCHUNKOUT_; ++k)
        acc += (double)partial[(size_t)(b * NCHUNKOUT_ + k) * (C_ * C_) + c * C_ + d];
    vals[d] = acc;
    __syncthreads();

    int r = 0;
    for (int jj = 0; jj < C_; ++jj) {
        const double vj = vals[jj];
        r += (int)((vj > acc) || (vj == acc && jj < d));   // stable descending rank
    }
    if (r < K_) idxb[blk * K_ + r] = d;
}

// fusion v5 (R6 structure + dual-pipe gather): stage HR[64][256] in LDS;
// each of 4 waves owns a c-quarter, 4 px/lane. k=0..23 gathered via
// ds_read_b128 (conflict-free); k=24..31 via direct global float4 loads
// (lane-consecutive -> coalesced; tile is L2-hot from staging). Global
// loads are issued at the top of each ci iteration so their L2 latency
// hides under the 24 ds_reads + fma stream. Same summation order as a
// pure-LDS 0..31 loop -> bit-identical output.
__global__ __launch_bounds__(256, 2) void fusion_gather_kernel(
    const float* __restrict__ HR, const float* __restrict__ LR,
    const int* __restrict__ idxb,
    const float* __restrict__ w1, const float* __restrict__ b1,
    const float* __restrict__ w2, const float* __restrict__ b2,
    float* __restrict__ out)
{
    __shared__ float hrS[C_][TILE_];   // 64 KB

    const int t = threadIdx.x;
    const int bid = blockIdx.x;        // 512 = B * (HW/TILE)
    const int b = bid >> 6;
    const int px0 = (bid & 63) * TILE_;

    const float* HRb = HR + (size_t)b * C_ * HW_;
    #pragma unroll
    for (int i = 0; i < 16; ++i) {
        const int f = i * 256 + t;
        const int c = f >> 6;
        const int q = f & 63;
        *reinterpret_cast<float4*>(&hrS[c][q * 4]) =
            *reinterpret_cast<const float4*>(&HRb[(size_t)c * HW_ + px0 + q * 4]);
    }
    __syncthreads();

    const int wv = t >> 6;             // wave id -> c-quarter
    const int lane = t & 63;
    const int p4 = lane * 4;           // this lane's 4 px within the tile

    const int* idxc = idxb + b * C_ * K_;
    const float w10 = w1[0];
    const float b1v = b1[0], w2v = w2[0], b2v = b2[0];

    #pragma unroll 1
    for (int ci = 0; ci < 16; ++ci) {
        const int c = wv * 16 + ci;

        // issue the global-pipe gathers first (k = 24..31), then LR
        float4 g[K_ - KSPLIT_];
        #pragma unroll
        for (int k = 0; k < K_ - KSPLIT_; ++k) {
            const int d = idxc[c * K_ + KSPLIT_ + k];            // uniform -> s_load
            g[k] = *reinterpret_cast<const float4*>(&HRb[(size_t)d * HW_ + px0 + p4]);
        }
        const float4 l4 = *reinterpret_cast<const float4*>(
            &LR[(size_t)(b * C_ + c) * HW_ + px0 + p4]);

        float acc[4] = {0.f, 0.f, 0.f, 0.f};
        float mx[4]  = {-1e30f, -1e30f, -1e30f, -1e30f};
        #pragma unroll
        for (int k = 0; k < KSPLIT_; ++k) {
            const int d = idxc[c * K_ + k];          // uniform -> s_load
            const float4 h = *reinterpret_cast<const float4*>(&hrS[d][p4]);
            const float wk = w1[k + 1];              // uniform -> SGPR
            acc[0] = fmaf(h.x, wk, acc[0]);
            acc[1] = fmaf(h.y, wk, acc[1]);
            acc[2] = fmaf(h.z, wk, acc[2]);
            acc[3] = fmaf(h.w, wk, acc[3]);
            mx[0] = fmaxf(mx[0], h.x);
            mx[1] = fmaxf(mx[1], h.y);
            mx[2] = fmaxf(mx[2], h.z);
            mx[3] = fmaxf(mx[3], h.w);
        }
        #pragma unroll
        for (int k = 0; k < K_ - KSPLIT_; ++k) {
            const float wk = w1[KSPLIT_ + k + 1];    // uniform -> SGPR
            acc[0] = fmaf(g[k].x, wk, acc[0]);
            acc[1] = fmaf(g[k].y, wk, acc[1]);
            acc[2] = fmaf(g[k].z, wk, acc[2]);
            acc[3] = fmaf(g[k].w, wk, acc[3]);
            mx[0] = fmaxf(mx[0], g[k].x);
            mx[1] = fmaxf(mx[1], g[k].y);
            mx[2] = fmaxf(mx[2], g[k].z);
            mx[3] = fmaxf(mx[3], g[k].w);
        }

        const float l[4] = {l4.x, l4.y, l4.z, l4.w};
        float o[4];
        #pragma unroll
        for (int p = 0; p < 4; ++p) {
            float f = fmaf(w10, l[p], acc[p]) + b1v;
            f = f >= 0.f ? f : NEG_SLOPE_ * f;
            f = fmaf(w2v, f, b2v);
            const float s = 1.f / (1.f + __expf(-mx[p]));
            o[p] = f * (1.f + s);
        }
        *reinterpret_cast<float4*>(&out[(size_t)(b * C_ + c) * HW_ + px0 + p4]) =
            make_float4(o[0], o[1], o[2], o[3]);
    }
}

extern "C" void kernel_launch(void* const* d_in, const int* in_sizes, int n_in,
                              void* d_out, int out_size, void* d_ws, size_t ws_size,
                              hipStream_t stream)
{
    const float* HR = (const float*)d_in[0];
    const float* LR = (const float*)d_in[1];
    const float* w1 = (const float*)d_in[2];
    const float* b1 = (const float*)d_in[3];
    const float* w2 = (const float*)d_in[4];
    const float* b2 = (const float*)d_in[5];
    float* out = (float*)d_out;

    float* partial = (float*)d_ws;
    int* idxb = (int*)((char*)d_ws + (size_t)B_ * NCHUNKOUT_ * C_ * C_ * sizeof(float));

    corr_partial_kernel<<<B_ * 64, 256, 0, stream>>>(LR, HR, partial);
    rank_kernel<<<B_ * C_, 64, 0, stream>>>(partial, idxb);
    fusion_gather_kernel<<<B_ * (HW_ / TILE_), 256, 0, stream>>>(HR, LR, idxb, w1, b1, w2, b2, out);
}